// Round 2
// baseline (263.076 us; speedup 1.0000x reference)
//
#include <hip/hip_runtime.h>
#include <hip/hip_bf16.h>
#include <cstddef>

#define T_SEQ 2048
#define D_HEAD 64
#define BR 128          // q-rows per block
#define BC 64           // key-tile
#define NTHREADS 512    // 8 waves
#define PAD 72          // LDS row stride (elems): 144 B, 16B-aligned, conflict-free frags

typedef __bf16 bf16x8 __attribute__((ext_vector_type(8)));
typedef float f32x4 __attribute__((ext_vector_type(4)));
typedef unsigned short u16x8 __attribute__((ext_vector_type(8)));

__device__ __forceinline__ unsigned short f2bf(float f) {
  union { float f; unsigned u; } c; c.f = f;
  return (unsigned short)((c.u + 0x7fffu + ((c.u >> 16) & 1u)) >> 16);  // RNE
}

__device__ __forceinline__ bf16x8 ldfrag(const unsigned short* p) {
  u16x8 t = *(const u16x8*)p;   // 16B aligned by construction
  return __builtin_bit_cast(bf16x8, t);
}

__device__ __forceinline__ f32x4 mfma16(bf16x8 a, bf16x8 b, f32x4 c) {
  return __builtin_amdgcn_mfma_f32_16x16x32_bf16(a, b, c, 0, 0, 0);
}

// ---------- mask pack: (T,T) int32 {0,1} -> 1 bit/elem in d_ws ----------
__global__ __launch_bounds__(256) void mask_pack(const int* __restrict__ maskg,
                                                 unsigned* __restrict__ mp) {
  const size_t total = (size_t)T_SEQ * T_SEQ;
  size_t idx = (size_t)blockIdx.x * blockDim.x + threadIdx.x;
  const size_t stride = (size_t)gridDim.x * blockDim.x;
  const int lane = threadIdx.x & 63;
  for (; idx < total; idx += stride) {
    int mv = maskg[idx];
    unsigned long long b = __ballot(mv != 0);
    if (lane == 0)       mp[idx >> 5] = (unsigned)b;          // bits 0..31
    else if (lane == 32) mp[idx >> 5] = (unsigned)(b >> 32);  // bits 32..63
  }
}

// A-frag: row = lane&15, k = 32*kk + 8*(lane>>4) + [0..7] contiguous
// B-frag: col = lane&15, same k slice
// D-frag: col = lane&15, row = 4*(lane>>4) + reg   [verified layout, learn_hip m89/m91]
template <bool PACKED>
__global__ __launch_bounds__(NTHREADS, 4) void attn_fused(   // 4 waves/EU -> 2 blocks/CU, VGPR<=128
    const float* __restrict__ qg, const float* __restrict__ kg,
    const float* __restrict__ vg, const int* __restrict__ maskg,
    const unsigned* __restrict__ mpk,
    float* __restrict__ outg, float* __restrict__ attng)
{
  __shared__ unsigned short qs[BR][PAD];      // Q tile bf16
  __shared__ unsigned short ks[BC][PAD];      // K tile bf16
  __shared__ unsigned short vt[D_HEAD][PAD];  // V^T tile bf16: vt[d][s]
  __shared__ unsigned short ps[BR][PAD];      // P tile bf16 (unnormalized exp)
  __shared__ float rsum[BR];

  // XCD-chunked swizzle: 512 blocks / 8 XCDs -> 4 heads per XCD (K/V L2-resident)
  int bid = blockIdx.x;
  int lin = (bid & 7) * 64 + (bid >> 3);
  int bh  = lin >> 4;            // 0..31
  int br0 = (lin & 15) * BR;     // q-row base

  const int tid  = threadIdx.x;
  const int lane = tid & 63;
  const int wid  = tid >> 6;
  const int wm = wid >> 1;       // 0..3: 32-row strip
  const int wn = wid & 1;        // 0..1: 32-col strip
  const int lr = lane & 15;
  const int lh = lane >> 4;

  const float scale = 0.125f;    // 1/sqrt(64)
  const float* qb = qg + ((size_t)bh * T_SEQ + br0) * D_HEAD;
  const float* kb = kg + (size_t)bh * T_SEQ * D_HEAD;
  const float* vb = vg + (size_t)bh * T_SEQ * D_HEAD;
  const int ROWW = T_SEQ / 32;   // mask words per row

  if (tid < BR) rsum[tid] = 0.f;

  // ---- stage Q (128x64 f32 -> bf16), coalesced float4 ----
  #pragma unroll
  for (int it = 0; it < 4; ++it) {
    int idx = it * NTHREADS + tid;
    int r = idx >> 4, c = (idx & 15) << 2;
    float4 f = *(const float4*)(qb + (size_t)r * D_HEAD + c);
    *(ushort4*)&qs[r][c] = make_ushort4(f2bf(f.x), f2bf(f.y), f2bf(f.z), f2bf(f.w));
  }

  f32x4 acc_o[2][2];
  const f32x4 zero4 = {0.f, 0.f, 0.f, 0.f};
  #pragma unroll
  for (int a = 0; a < 2; ++a)
    #pragma unroll
    for (int b = 0; b < 2; ++b) acc_o[a][b] = zero4;
  float psum[2][4] = {{0.f,0.f,0.f,0.f},{0.f,0.f,0.f,0.f}};

  __syncthreads();

  // =================== PASS 1: rowsums + O (unnormalized PV) ===================
  for (int kt = 0; kt < T_SEQ / BC; ++kt) {
    const int kb0 = kt * BC;
    // stage K tile + V^T tile
    #pragma unroll
    for (int it = 0; it < 2; ++it) {
      int idx = it * NTHREADS + tid;
      int r = idx >> 4, c = (idx & 15) << 2;
      float4 f = *(const float4*)(kb + (size_t)(kb0 + r) * D_HEAD + c);
      *(ushort4*)&ks[r][c] = make_ushort4(f2bf(f.x), f2bf(f.y), f2bf(f.z), f2bf(f.w));
      float4 g = *(const float4*)(vb + (size_t)(kb0 + r) * D_HEAD + c);
      vt[c + 0][r] = f2bf(g.x);
      vt[c + 1][r] = f2bf(g.y);
      vt[c + 2][r] = f2bf(g.z);
      vt[c + 3][r] = f2bf(g.w);
    }
    __syncthreads();

    // S = Q K^T : wave computes 32x32
    f32x4 sc[2][2];
    #pragma unroll
    for (int a = 0; a < 2; ++a)
      #pragma unroll
      for (int b = 0; b < 2; ++b) sc[a][b] = zero4;

    #pragma unroll
    for (int kk = 0; kk < 2; ++kk) {
      const int ke = kk * 32 + lh * 8;
      bf16x8 af[2], bfq[2];
      #pragma unroll
      for (int mt = 0; mt < 2; ++mt) af[mt]  = ldfrag(&qs[wm*32 + mt*16 + lr][ke]);
      #pragma unroll
      for (int nt = 0; nt < 2; ++nt) bfq[nt] = ldfrag(&ks[wn*32 + nt*16 + lr][ke]);
      #pragma unroll
      for (int mt = 0; mt < 2; ++mt)
        #pragma unroll
        for (int nt = 0; nt < 2; ++nt)
          sc[mt][nt] = mfma16(af[mt], bfq[nt], sc[mt][nt]);
    }

    // exp + mask + psum + write P tile (one mask word per (mt,r) row)
    #pragma unroll
    for (int mt = 0; mt < 2; ++mt)
      #pragma unroll
      for (int r = 0; r < 4; ++r) {
        int row = wm*32 + mt*16 + lh*4 + r;
        unsigned wbits = 0;
        if (PACKED) wbits = mpk[(size_t)(br0 + row) * ROWW + (kb0 >> 5) + wn];
        #pragma unroll
        for (int nt = 0; nt < 2; ++nt) {
          int col = wn*32 + nt*16 + lr;
          int mv;
          if (PACKED) mv = (wbits >> (nt*16 + lr)) & 1;
          else        mv = maskg[(size_t)(br0 + row) * T_SEQ + (kb0 + col)];
          float p = mv ? __expf(sc[mt][nt][r] * scale) : 0.f;
          psum[mt][r] += p;
          ps[row][col] = f2bf(p);
        }
      }
    __syncthreads();

    // O += P * V  (B-frags contiguous thanks to V^T staging)
    #pragma unroll
    for (int kk = 0; kk < 2; ++kk) {
      const int ke = kk * 32 + lh * 8;
      bf16x8 pa[2], vf[2];
      #pragma unroll
      for (int mt = 0; mt < 2; ++mt) pa[mt] = ldfrag(&ps[wm*32 + mt*16 + lr][ke]);
      #pragma unroll
      for (int nt = 0; nt < 2; ++nt) vf[nt] = ldfrag(&vt[wn*32 + nt*16 + lr][ke]);
      #pragma unroll
      for (int mt = 0; mt < 2; ++mt)
        #pragma unroll
        for (int nt = 0; nt < 2; ++nt)
          acc_o[mt][nt] = mfma16(pa[mt], vf[nt], acc_o[mt][nt]);
    }
    __syncthreads();
  }

  // rowsum: reduce over 16 col-lanes, then combine wn=0/1 via LDS atomic (deterministic order-free: fp add of 2 values)
  #pragma unroll
  for (int mt = 0; mt < 2; ++mt)
    #pragma unroll
    for (int r = 0; r < 4; ++r) {
      float sv = psum[mt][r];
      sv += __shfl_xor(sv, 1);
      sv += __shfl_xor(sv, 2);
      sv += __shfl_xor(sv, 4);
      sv += __shfl_xor(sv, 8);
      if (lr == 0) atomicAdd(&rsum[wm*32 + mt*16 + lh*4 + r], sv);
    }
  __syncthreads();

  float invs[2][4];
  #pragma unroll
  for (int mt = 0; mt < 2; ++mt)
    #pragma unroll
    for (int r = 0; r < 4; ++r)
      invs[mt][r] = 1.0f / rsum[wm*32 + mt*16 + lh*4 + r];

  // write O (normalize here)
  float* ob = outg + ((size_t)bh * T_SEQ + br0) * D_HEAD;
  #pragma unroll
  for (int mt = 0; mt < 2; ++mt)
    #pragma unroll
    for (int nt = 0; nt < 2; ++nt)
      #pragma unroll
      for (int r = 0; r < 4; ++r) {
        int row = wm*32 + mt*16 + lh*4 + r;
        int col = wn*32 + nt*16 + lr;
        ob[(size_t)row * D_HEAD + col] = acc_o[mt][nt][r] * invs[mt][r];
      }

  // =================== PASS 2: recompute S, write normalized attn ===================
  float* ab = attng + (size_t)bh * T_SEQ * T_SEQ + (size_t)br0 * T_SEQ;
  for (int kt = 0; kt < T_SEQ / BC; ++kt) {
    const int kb0 = kt * BC;
    __syncthreads();  // guard ks reuse
    #pragma unroll
    for (int it = 0; it < 2; ++it) {
      int idx = it * NTHREADS + tid;
      int r = idx >> 4, c = (idx & 15) << 2;
      float4 f = *(const float4*)(kb + (size_t)(kb0 + r) * D_HEAD + c);
      *(ushort4*)&ks[r][c] = make_ushort4(f2bf(f.x), f2bf(f.y), f2bf(f.z), f2bf(f.w));
    }
    __syncthreads();

    f32x4 sc[2][2];
    #pragma unroll
    for (int a = 0; a < 2; ++a)
      #pragma unroll
      for (int b = 0; b < 2; ++b) sc[a][b] = zero4;

    #pragma unroll
    for (int kk = 0; kk < 2; ++kk) {
      const int ke = kk * 32 + lh * 8;
      bf16x8 af[2], bfq[2];
      #pragma unroll
      for (int mt = 0; mt < 2; ++mt) af[mt]  = ldfrag(&qs[wm*32 + mt*16 + lr][ke]);
      #pragma unroll
      for (int nt = 0; nt < 2; ++nt) bfq[nt] = ldfrag(&ks[wn*32 + nt*16 + lr][ke]);
      #pragma unroll
      for (int mt = 0; mt < 2; ++mt)
        #pragma unroll
        for (int nt = 0; nt < 2; ++nt)
          sc[mt][nt] = mfma16(af[mt], bfq[nt], sc[mt][nt]);
    }

    #pragma unroll
    for (int mt = 0; mt < 2; ++mt)
      #pragma unroll
      for (int r = 0; r < 4; ++r) {
        int row = wm*32 + mt*16 + lh*4 + r;
        unsigned wbits = 0;
        if (PACKED) wbits = mpk[(size_t)(br0 + row) * ROWW + (kb0 >> 5) + wn];
        #pragma unroll
        for (int nt = 0; nt < 2; ++nt) {
          int col = wn*32 + nt*16 + lr;
          int mv;
          if (PACKED) mv = (wbits >> (nt*16 + lr)) & 1;
          else        mv = maskg[(size_t)(br0 + row) * T_SEQ + (kb0 + col)];
          float p = mv ? __expf(sc[mt][nt][r] * scale) * invs[mt][r] : 0.f;
          ab[(size_t)row * T_SEQ + kb0 + col] = p;
        }
      }
  }
}

extern "C" void kernel_launch(void* const* d_in, const int* in_sizes, int n_in,
                              void* d_out, int out_size, void* d_ws, size_t ws_size,
                              hipStream_t stream) {
  const float* q = (const float*)d_in[0];
  const float* k = (const float*)d_in[1];
  const float* v = (const float*)d_in[2];
  const int* mask = (const int*)d_in[3];
  float* out = (float*)d_out;                           // (B,H,T,D) f32
  float* attn = out + (size_t)2 * 16 * T_SEQ * D_HEAD;  // (B,H,T,T) f32

  const size_t packed_bytes = (size_t)T_SEQ * T_SEQ / 8;  // 512 KB
  if (ws_size >= packed_bytes) {
    unsigned* mp = (unsigned*)d_ws;
    mask_pack<<<dim3(2048), 256, 0, stream>>>(mask, mp);
    attn_fused<true><<<dim3(512), NTHREADS, 0, stream>>>(q, k, v, mask, mp, out, attn);
  } else {
    attn_fused<false><<<dim3(512), NTHREADS, 0, stream>>>(q, k, v, mask, nullptr, out, attn);
  }
}

// Round 3
// 259.084 us; speedup vs baseline: 1.0154x; 1.0154x over previous
//
#include <hip/hip_runtime.h>
#include <hip/hip_bf16.h>
#include <cstddef>

#define T_SEQ 2048
#define D_HEAD 64
#define BR 128          // q-rows per block
#define BC 64           // key-tile
#define NTHREADS 512    // 8 waves
#define PAD 72          // LDS row stride (elems): 144 B, 16B-aligned
#define NKT (T_SEQ / BC)

typedef __bf16 bf16x8 __attribute__((ext_vector_type(8)));
typedef float f32x4 __attribute__((ext_vector_type(4)));
typedef unsigned short u16x8 __attribute__((ext_vector_type(8)));

__device__ __forceinline__ unsigned short f2bf(float f) {
  __bf16 h = (__bf16)f;                    // native RNE cast; compiler packs
  return __builtin_bit_cast(unsigned short, h);
}

__device__ __forceinline__ bf16x8 ldfrag(const unsigned short* p) {
  u16x8 t = *(const u16x8*)p;
  return __builtin_bit_cast(bf16x8, t);
}

__device__ __forceinline__ f32x4 mfma16(bf16x8 a, bf16x8 b, f32x4 c) {
  return __builtin_amdgcn_mfma_f32_16x16x32_bf16(a, b, c, 0, 0, 0);
}

// raw barrier: NO vmcnt drain (stores stay in flight across it)
__device__ __forceinline__ void bar_sync() {
  asm volatile("" ::: "memory");
  __builtin_amdgcn_s_barrier();
  asm volatile("" ::: "memory");
}
__device__ __forceinline__ void lds_fence() {
  asm volatile("s_waitcnt lgkmcnt(0)" ::: "memory");
}

// ---------- mask pack: (T,T) int32 {0,1} -> 1 bit/elem in d_ws ----------
__global__ __launch_bounds__(256) void mask_pack(const int* __restrict__ maskg,
                                                 unsigned* __restrict__ mp) {
  const size_t total = (size_t)T_SEQ * T_SEQ;
  size_t idx = (size_t)blockIdx.x * blockDim.x + threadIdx.x;
  const size_t stride = (size_t)gridDim.x * blockDim.x;
  const int lane = threadIdx.x & 63;
  for (; idx < total; idx += stride) {
    int mv = maskg[idx];
    unsigned long long b = __ballot(mv != 0);
    if (lane == 0)       mp[idx >> 5] = (unsigned)b;
    else if (lane == 32) mp[idx >> 5] = (unsigned)(b >> 32);
  }
}

// A-frag: row=lane&15, k=32*kk+8*(lane>>4)+[0..7]; D-frag: col=lane&15, row=4*(lane>>4)+reg
template <bool PACKED>
__global__ __launch_bounds__(NTHREADS, 4) void attn_fused(
    const float* __restrict__ qg, const float* __restrict__ kg,
    const float* __restrict__ vg, const int* __restrict__ maskg,
    const unsigned* __restrict__ mpk,
    float* __restrict__ outg, float* __restrict__ attng)
{
  __shared__ unsigned short qs[BR][PAD];
  __shared__ unsigned short ks[2][BC][PAD];       // double-buffered K
  __shared__ unsigned short vt[2][D_HEAD][PAD];   // double-buffered V^T
  __shared__ unsigned short ps[BR][PAD];
  __shared__ float rsum[BR];

  int bid = blockIdx.x;
  int lin = (bid & 7) * 64 + (bid >> 3);   // XCD-chunked swizzle
  int bh  = lin >> 4;
  int br0 = (lin & 15) * BR;

  const int tid  = threadIdx.x;
  const int lane = tid & 63;
  const int wid  = tid >> 6;
  const int wm = wid >> 1;
  const int wn = wid & 1;
  const int lr = lane & 15;
  const int lh = lane >> 4;
  const int sr = tid >> 4;            // staging row 0..31 (+32*it)
  const int scol = (tid & 15) << 2;   // staging col

  const float scale = 0.125f;
  const float* qb = qg + ((size_t)bh * T_SEQ + br0) * D_HEAD;
  const float* kb = kg + (size_t)bh * T_SEQ * D_HEAD;
  const float* vb = vg + (size_t)bh * T_SEQ * D_HEAD;
  const int ROWW = T_SEQ / 32;

  if (tid < BR) rsum[tid] = 0.f;

  // ---- stage Q ----
  #pragma unroll
  for (int it = 0; it < 4; ++it) {
    int idx = it * NTHREADS + tid;
    int r = idx >> 4, c = (idx & 15) << 2;
    float4 f = *(const float4*)(qb + (size_t)r * D_HEAD + c);
    *(ushort4*)&qs[r][c] = make_ushort4(f2bf(f.x), f2bf(f.y), f2bf(f.z), f2bf(f.w));
  }
  // ---- stage K/V tile 0 into buf 0 ----
  #pragma unroll
  for (int it = 0; it < 2; ++it) {
    int r = it * 32 + sr;
    float4 f = *(const float4*)(kb + (size_t)r * D_HEAD + scol);
    *(ushort4*)&ks[0][r][scol] = make_ushort4(f2bf(f.x), f2bf(f.y), f2bf(f.z), f2bf(f.w));
    float4 g = *(const float4*)(vb + (size_t)r * D_HEAD + scol);
    vt[0][scol + 0][r] = f2bf(g.x);
    vt[0][scol + 1][r] = f2bf(g.y);
    vt[0][scol + 2][r] = f2bf(g.z);
    vt[0][scol + 3][r] = f2bf(g.w);
  }
  // mask words for tile 0
  unsigned mw[2][4];
  if constexpr (PACKED) {
    #pragma unroll
    for (int mt = 0; mt < 2; ++mt)
      #pragma unroll
      for (int r = 0; r < 4; ++r)
        mw[mt][r] = mpk[(size_t)(br0 + wm*32 + mt*16 + lh*4 + r) * ROWW + wn];
  }

  f32x4 acc_o[2][2];
  const f32x4 zero4 = {0.f, 0.f, 0.f, 0.f};
  #pragma unroll
  for (int a = 0; a < 2; ++a)
    #pragma unroll
    for (int b = 0; b < 2; ++b) acc_o[a][b] = zero4;
  float psum[2][4] = {{0.f,0.f,0.f,0.f},{0.f,0.f,0.f,0.f}};

  __syncthreads();   // prologue: full drain OK (no store backlog yet)

  // =================== PASS 1 ===================
  for (int kt = 0; kt < NKT; ++kt) {
    const int cur = kt & 1, nxt = cur ^ 1;
    const int kn  = (kt + 1 < NKT) ? kt + 1 : kt;   // tail: redundant reload
    const int kb0 = kt * BC, kbn = kn * BC;

    // (1) prefetch next K/V + next mask words — ISSUED BEFORE anything else
    float4 pfk0 = *(const float4*)(kb + (size_t)(kbn + sr     ) * D_HEAD + scol);
    float4 pfk1 = *(const float4*)(kb + (size_t)(kbn + sr + 32) * D_HEAD + scol);
    float4 pfv0 = *(const float4*)(vb + (size_t)(kbn + sr     ) * D_HEAD + scol);
    float4 pfv1 = *(const float4*)(vb + (size_t)(kbn + sr + 32) * D_HEAD + scol);
    unsigned mwn[2][4];
    if constexpr (PACKED) {
      #pragma unroll
      for (int mt = 0; mt < 2; ++mt)
        #pragma unroll
        for (int r = 0; r < 4; ++r)
          mwn[mt][r] = mpk[(size_t)(br0 + wm*32 + mt*16 + lh*4 + r) * ROWW + kn*2 + wn];
    }
    __builtin_amdgcn_sched_barrier(0);   // pin prefetch issue before compute

    // (2) S = Q K^T from buf cur
    f32x4 sc[2][2];
    #pragma unroll
    for (int a = 0; a < 2; ++a)
      #pragma unroll
      for (int b = 0; b < 2; ++b) sc[a][b] = zero4;
    #pragma unroll
    for (int kk = 0; kk < 2; ++kk) {
      const int ke = kk * 32 + lh * 8;
      bf16x8 af[2], bfq[2];
      #pragma unroll
      for (int mt = 0; mt < 2; ++mt) af[mt]  = ldfrag(&qs[wm*32 + mt*16 + lr][ke]);
      #pragma unroll
      for (int nt = 0; nt < 2; ++nt) bfq[nt] = ldfrag(&ks[cur][wn*32 + nt*16 + lr][ke]);
      #pragma unroll
      for (int mt = 0; mt < 2; ++mt)
        #pragma unroll
        for (int nt = 0; nt < 2; ++nt)
          sc[mt][nt] = mfma16(af[mt], bfq[nt], sc[mt][nt]);
    }

    // (3) exp + mask + psum + P write (mask already in regs: no vmem wait here)
    #pragma unroll
    for (int mt = 0; mt < 2; ++mt)
      #pragma unroll
      for (int r = 0; r < 4; ++r) {
        int row = wm*32 + mt*16 + lh*4 + r;
        #pragma unroll
        for (int nt = 0; nt < 2; ++nt) {
          int col = wn*32 + nt*16 + lr;
          int mv;
          if constexpr (PACKED) mv = (mw[mt][r] >> (nt*16 + lr)) & 1;
          else mv = maskg[(size_t)(br0 + row) * T_SEQ + (kb0 + col)];
          float p = mv ? __expf(sc[mt][nt][r] * scale) : 0.f;
          psum[mt][r] += p;
          ps[row][col] = f2bf(p);
        }
      }
    lds_fence(); bar_sync();   // P ready; prefetch loads still in flight

    // (4) O += P * V from buf cur
    #pragma unroll
    for (int kk = 0; kk < 2; ++kk) {
      const int ke = kk * 32 + lh * 8;
      bf16x8 pa[2], vf[2];
      #pragma unroll
      for (int mt = 0; mt < 2; ++mt) pa[mt] = ldfrag(&ps[wm*32 + mt*16 + lr][ke]);
      #pragma unroll
      for (int nt = 0; nt < 2; ++nt) vf[nt] = ldfrag(&vt[cur][wn*32 + nt*16 + lr][ke]);
      #pragma unroll
      for (int mt = 0; mt < 2; ++mt)
        #pragma unroll
        for (int nt = 0; nt < 2; ++nt)
          acc_o[mt][nt] = mfma16(pa[mt], vf[nt], acc_o[mt][nt]);
    }

    // (5) land prefetched tile into buf nxt (counted vmcnt wait at use)
    *(ushort4*)&ks[nxt][sr     ][scol] = make_ushort4(f2bf(pfk0.x), f2bf(pfk0.y), f2bf(pfk0.z), f2bf(pfk0.w));
    *(ushort4*)&ks[nxt][sr + 32][scol] = make_ushort4(f2bf(pfk1.x), f2bf(pfk1.y), f2bf(pfk1.z), f2bf(pfk1.w));
    vt[nxt][scol + 0][sr     ] = f2bf(pfv0.x);
    vt[nxt][scol + 1][sr     ] = f2bf(pfv0.y);
    vt[nxt][scol + 2][sr     ] = f2bf(pfv0.z);
    vt[nxt][scol + 3][sr     ] = f2bf(pfv0.w);
    vt[nxt][scol + 0][sr + 32] = f2bf(pfv1.x);
    vt[nxt][scol + 1][sr + 32] = f2bf(pfv1.y);
    vt[nxt][scol + 2][sr + 32] = f2bf(pfv1.z);
    vt[nxt][scol + 3][sr + 32] = f2bf(pfv1.w);
    lds_fence(); bar_sync();

    if constexpr (PACKED) {
      #pragma unroll
      for (int mt = 0; mt < 2; ++mt)
        #pragma unroll
        for (int r = 0; r < 4; ++r) mw[mt][r] = mwn[mt][r];
    }
  }

  // rowsum reduce
  #pragma unroll
  for (int mt = 0; mt < 2; ++mt)
    #pragma unroll
    for (int r = 0; r < 4; ++r) {
      float sv = psum[mt][r];
      sv += __shfl_xor(sv, 1);
      sv += __shfl_xor(sv, 2);
      sv += __shfl_xor(sv, 4);
      sv += __shfl_xor(sv, 8);
      if (lr == 0) atomicAdd(&rsum[wm*32 + mt*16 + lh*4 + r], sv);
    }
  __syncthreads();

  float invs[2][4];
  #pragma unroll
  for (int mt = 0; mt < 2; ++mt)
    #pragma unroll
    for (int r = 0; r < 4; ++r)
      invs[mt][r] = 1.0f / rsum[wm*32 + mt*16 + lh*4 + r];

  float* ob = outg + ((size_t)bh * T_SEQ + br0) * D_HEAD;
  #pragma unroll
  for (int mt = 0; mt < 2; ++mt)
    #pragma unroll
    for (int nt = 0; nt < 2; ++nt)
      #pragma unroll
      for (int r = 0; r < 4; ++r) {
        int row = wm*32 + mt*16 + lh*4 + r;
        int col = wn*32 + nt*16 + lr;
        ob[(size_t)row * D_HEAD + col] = acc_o[mt][nt][r] * invs[mt][r];
      }

  // =================== PASS 2: recompute S, write normalized attn ===================
  // prologue: stage K tile 0 into buf 0 (out-stores drain once here — cheap)
  #pragma unroll
  for (int it = 0; it < 2; ++it) {
    int r = it * 32 + sr;
    float4 f = *(const float4*)(kb + (size_t)r * D_HEAD + scol);
    *(ushort4*)&ks[0][r][scol] = make_ushort4(f2bf(f.x), f2bf(f.y), f2bf(f.z), f2bf(f.w));
  }
  if constexpr (PACKED) {
    #pragma unroll
    for (int mt = 0; mt < 2; ++mt)
      #pragma unroll
      for (int r = 0; r < 4; ++r)
        mw[mt][r] = mpk[(size_t)(br0 + wm*32 + mt*16 + lh*4 + r) * ROWW + wn];
  }
  __syncthreads();

  float* ab = attng + (size_t)bh * T_SEQ * T_SEQ + (size_t)br0 * T_SEQ;
  for (int kt = 0; kt < NKT; ++kt) {
    const int cur = kt & 1, nxt = cur ^ 1;
    const int kn  = (kt + 1 < NKT) ? kt + 1 : kt;
    const int kb0 = kt * BC, kbn = kn * BC;

    // (1) prefetch next K + next mask — BEFORE this tile's stores
    float4 pfk0 = *(const float4*)(kb + (size_t)(kbn + sr     ) * D_HEAD + scol);
    float4 pfk1 = *(const float4*)(kb + (size_t)(kbn + sr + 32) * D_HEAD + scol);
    unsigned mwn[2][4];
    if constexpr (PACKED) {
      #pragma unroll
      for (int mt = 0; mt < 2; ++mt)
        #pragma unroll
        for (int r = 0; r < 4; ++r)
          mwn[mt][r] = mpk[(size_t)(br0 + wm*32 + mt*16 + lh*4 + r) * ROWW + kn*2 + wn];
    }
    __builtin_amdgcn_sched_barrier(0);

    // (2) S = Q K^T
    f32x4 sc[2][2];
    #pragma unroll
    for (int a = 0; a < 2; ++a)
      #pragma unroll
      for (int b = 0; b < 2; ++b) sc[a][b] = zero4;
    #pragma unroll
    for (int kk = 0; kk < 2; ++kk) {
      const int ke = kk * 32 + lh * 8;
      bf16x8 af[2], bfq[2];
      #pragma unroll
      for (int mt = 0; mt < 2; ++mt) af[mt]  = ldfrag(&qs[wm*32 + mt*16 + lr][ke]);
      #pragma unroll
      for (int nt = 0; nt < 2; ++nt) bfq[nt] = ldfrag(&ks[cur][wn*32 + nt*16 + lr][ke]);
      #pragma unroll
      for (int mt = 0; mt < 2; ++mt)
        #pragma unroll
        for (int nt = 0; nt < 2; ++nt)
          sc[mt][nt] = mfma16(af[mt], bfq[nt], sc[mt][nt]);
    }

    // (3) normalized attn stores (stores pile up behind prefetch loads — never drained)
    #pragma unroll
    for (int mt = 0; mt < 2; ++mt)
      #pragma unroll
      for (int r = 0; r < 4; ++r) {
        int row = wm*32 + mt*16 + lh*4 + r;
        #pragma unroll
        for (int nt = 0; nt < 2; ++nt) {
          int col = wn*32 + nt*16 + lr;
          int mv;
          if constexpr (PACKED) mv = (mw[mt][r] >> (nt*16 + lr)) & 1;
          else mv = maskg[(size_t)(br0 + row) * T_SEQ + (kb0 + col)];
          float p = mv ? __expf(sc[mt][nt][r] * scale) * invs[mt][r] : 0.f;
          ab[(size_t)row * T_SEQ + kb0 + col] = p;
        }
      }

    // (4) land prefetched K into buf nxt
    *(ushort4*)&ks[nxt][sr     ][scol] = make_ushort4(f2bf(pfk0.x), f2bf(pfk0.y), f2bf(pfk0.z), f2bf(pfk0.w));
    *(ushort4*)&ks[nxt][sr + 32][scol] = make_ushort4(f2bf(pfk1.x), f2bf(pfk1.y), f2bf(pfk1.z), f2bf(pfk1.w));
    lds_fence(); bar_sync();

    if constexpr (PACKED) {
      #pragma unroll
      for (int mt = 0; mt < 2; ++mt)
        #pragma unroll
        for (int r = 0; r < 4; ++r) mw[mt][r] = mwn[mt][r];
    }
  }
}

extern "C" void kernel_launch(void* const* d_in, const int* in_sizes, int n_in,
                              void* d_out, int out_size, void* d_ws, size_t ws_size,
                              hipStream_t stream) {
  const float* q = (const float*)d_in[0];
  const float* k = (const float*)d_in[1];
  const float* v = (const float*)d_in[2];
  const int* mask = (const int*)d_in[3];
  float* out = (float*)d_out;
  float* attn = out + (size_t)2 * 16 * T_SEQ * D_HEAD;

  const size_t packed_bytes = (size_t)T_SEQ * T_SEQ / 8;
  if (ws_size >= packed_bytes) {
    unsigned* mp = (unsigned*)d_ws;
    mask_pack<<<dim3(2048), 256, 0, stream>>>(mask, mp);
    attn_fused<true><<<dim3(512), NTHREADS, 0, stream>>>(q, k, v, mask, mp, out, attn);
  } else {
    attn_fused<false><<<dim3(512), NTHREADS, 0, stream>>>(q, k, v, mask, nullptr, out, attn);
  }
}